// Round 7
// baseline (190.805 us; speedup 1.0000x reference)
//
#include <hip/hip_runtime.h>

typedef __bf16 bf16x8 __attribute__((ext_vector_type(8)));
typedef float floatx16 __attribute__((ext_vector_type(16)));
typedef float floatx4 __attribute__((ext_vector_type(4)));

#define T_ 4096
#define XSTR 40     // proj x-tile row stride (shorts)
#define NSPB 272    // split-blocks per batch: sum_{qt=0..31} ceil((qt+1)/2)

// ws layout (bytes)
#define WT_OFF 0u
#define Q_OFF  393216u
#define K_OFF  2490368u
#define V_OFF  4587520u
#define OP_OFF 6684672u
#define ML_OFF 42336256u   // OP_OFF + 4*NSPB*8192*4
#define VT_OFF 44040192u   // V transposed [4][64][4096] bf16 (2MB)

__device__ __forceinline__ unsigned short bf16bits(float f) {
  __bf16 h = (__bf16)f;
  return __builtin_bit_cast(unsigned short, h);
}

// async global->LDS 16B: LDS dest is wave-uniform base + lane*16 (m97/m104)
__device__ __forceinline__ void async16(const void* g, void* l) {
  __builtin_amdgcn_global_load_lds((const __attribute__((address_space(1))) void*)g,
                                   (__attribute__((address_space(3))) void*)l, 16, 0, 0);
}

// ---------------- kernel 0: W -> W^T bf16, fold softmax scale into Wq ----------------
__global__ void wprep(const float* __restrict__ Wq, const float* __restrict__ Wk,
                      const float* __restrict__ Wv, __bf16* __restrict__ Wtg) {
  int idx = blockIdx.x * 256 + threadIdx.x;      // 0..196607
  int mat = idx >> 16;
  int r = idx & 65535;
  int h = r & 63;
  int k = r >> 6;
  const float* W = (mat == 0) ? Wq : ((mat == 1) ? Wk : Wv);
  float v = W[k * 64 + h];
  if (mat == 0) v *= 0.03125f * 1.4426950408889634f;  // C^-0.5 * log2(e)
  Wtg[(size_t)(mat * 64 + h) * 1024 + k] = (__bf16)v;
}

// ---------------- kernel 1: QKV projection (unchanged from R6 for attribution) -------
__global__ __launch_bounds__(256, 4) void proj(const float* __restrict__ x,
                                               const __bf16* __restrict__ Wtg,
                                               __bf16* __restrict__ Qp,
                                               __bf16* __restrict__ Kp,
                                               __bf16* __restrict__ Vp) {
  __shared__ __align__(16) unsigned short sm[2 * 16 * XSTR + 2 * 6144];
  unsigned short* xt = sm;
  unsigned short* wt = sm + 2 * 16 * XSTR;

  const int tid = threadIdx.x;
  const int wave = tid >> 6, lane = tid & 63;
  const int l15 = lane & 15, quad = lane >> 4;
  const size_t row0 = (size_t)blockIdx.x * 16;

  const int xrow = tid >> 3, xc4 = (tid & 7) * 4;
  const float* xsrc = (tid < 128) ? (x + (row0 + xrow) * 1024 + xc4) : x;
  const int wR0 = tid >> 2, wsl = tid & 3;

  floatx4 acc[3];
#pragma unroll
  for (int t = 0; t < 3; t++)
#pragma unroll
    for (int i = 0; i < 4; i++) acc[t][i] = 0.0f;

  {
    unsigned short* wb = wt;
#pragma unroll
    for (int i = 0; i < 3; i++) {
      int R = wR0 + i * 64;
      int sg = wsl ^ (R & 3);
      async16((const char*)Wtg + (size_t)R * 2048 + sg * 16,
              (char*)(wb + (i * 256 + wave * 64) * 8));
    }
    if (tid < 128) {
      float4 f = *(const float4*)(xsrc);
      unsigned short hb[4];
      hb[0] = bf16bits(f.x); hb[1] = bf16bits(f.y); hb[2] = bf16bits(f.z); hb[3] = bf16bits(f.w);
      *(uint2*)&xt[xrow * XSTR + xc4] = *(uint2*)(hb);
    }
  }
  __syncthreads();

  for (int kc = 0; kc < 32; ++kc) {
    const int cur = kc & 1;
    if (kc < 31) {
      unsigned short* wb = wt + (cur ^ 1) * 6144;
#pragma unroll
      for (int i = 0; i < 3; i++) {
        int R = wR0 + i * 64;
        int sg = wsl ^ (R & 3);
        async16((const char*)Wtg + (size_t)R * 2048 + (kc + 1) * 64 + sg * 16,
                (char*)(wb + (i * 256 + wave * 64) * 8));
      }
      if (tid < 128) {
        float4 f = *(const float4*)(xsrc + (kc + 1) * 32);
        unsigned short hb[4];
        hb[0] = bf16bits(f.x); hb[1] = bf16bits(f.y); hb[2] = bf16bits(f.z); hb[3] = bf16bits(f.w);
        *(uint2*)&xt[(cur ^ 1) * 16 * XSTR + xrow * XSTR + xc4] = *(uint2*)(hb);
      }
    }
    const unsigned short* xb = xt + cur * 16 * XSTR;
    const unsigned short* wb = wt + cur * 6144;
    bf16x8 a = *(const bf16x8*)&xb[l15 * XSTR + quad * 8];
#pragma unroll
    for (int ht = 0; ht < 3; ++ht) {
      int Rg = wave * 48 + ht * 16 + l15;
      bf16x8 b = *(const bf16x8*)&wb[Rg * 32 + ((quad ^ (Rg & 3))) * 8];
      acc[ht] = __builtin_amdgcn_mfma_f32_16x16x32_bf16(a, b, acc[ht], 0, 0, 0);
    }
    __syncthreads();
  }
#pragma unroll
  for (int ht = 0; ht < 3; ++ht) {
    int g0 = wave * 48 + ht * 16;
    int mat = g0 >> 6, h0 = g0 & 63;
    __bf16* outp = (mat == 0) ? Qp : ((mat == 1) ? Kp : Vp);
#pragma unroll
    for (int r = 0; r < 4; r++) {
      size_t row = row0 + quad * 4 + r;
      outp[row * 64 + h0 + l15] = (__bf16)acc[ht][r];
    }
  }
}

// ---------------- kernel 1b: V transpose  Vp[b][t][h] -> Vt[b][h][t] ----------------
__global__ __launch_bounds__(256) void vtr(const __bf16* __restrict__ Vp,
                                           __bf16* __restrict__ Vt) {
  __shared__ __align__(16) unsigned short tl[64 * 72];
  const int tid = threadIdx.x;
  const int bb = blockIdx.x >> 6, tt = blockIdx.x & 63;
  const __bf16* src = Vp + ((size_t)bb * 4096 + tt * 64) * 64;
  int row = tid >> 2, c16 = (tid & 3) * 16;
  *(uint4*)&tl[row * 72 + c16] = *(const uint4*)(src + row * 64 + c16);
  *(uint4*)&tl[row * 72 + c16 + 8] = *(const uint4*)(src + row * 64 + c16 + 8);
  __syncthreads();
  unsigned short ob[16];
#pragma unroll
  for (int i = 0; i < 16; i++) ob[i] = tl[(c16 + i) * 72 + row];
  __bf16* dst = Vt + (size_t)bb * 262144 + (size_t)row * 4096 + tt * 64 + c16;
  *(uint4*)dst = *(uint4*)(ob);
  *(uint4*)(dst + 8) = *(uint4*)(ob + 8);
}

// ---------------- kernel 2: flash attention pass 1 — NO LDS / NO BARRIERS in loop ----
// K & V^T fragments straight from global (L2-resident); P C-layout -> B-layout via
// __shfl_xor(32) in registers. Waves fully independent.
__global__ __launch_bounds__(256, 3) void attn1(const __bf16* __restrict__ Qp,
                                                const __bf16* __restrict__ Kp,
                                                const __bf16* __restrict__ Vt,
                                                float* __restrict__ Opart,
                                                float* __restrict__ mlpart) {
  __shared__ __align__(16) float Oe[128 * 68];   // epilogue only (34816B)

  const int tid = threadIdx.x;
  const int wave = tid >> 6, lane = tid & 63;
  const int l31 = lane & 31, half = lane >> 5;

  const int bid = blockIdx.x;
  const int b = bid / NSPB;
  const int f = bid - b * NSPB;
  int qt = 0, cum = 0;
  for (;;) { int s = (qt + 2) >> 1; if (f < cum + s) break; cum += s; qt++; }
  const int si = f - cum;
  const int S = (qt + 2) >> 1;
  const int n_iters = 2 * (qt + 1);
  const int bbase = n_iters / S, rem = n_iters % S;
  const int it0 = si * bbase + (si < rem ? si : rem);
  const int it1 = it0 + bbase + (si < rem ? 1 : 0);

  const int qb = qt * 128;
  const size_t brow = (size_t)b * 4096;

  bf16x8 qf[4];
  {
    const __bf16* qptr = Qp + (brow + qb + wave * 32 + l31) * 64 + half * 8;
#pragma unroll
    for (int ks = 0; ks < 4; ks++) qf[ks] = *(const bf16x8*)(qptr + ks * 16);
  }

  floatx16 o0, o1;
#pragma unroll
  for (int r = 0; r < 16; r++) { o0[r] = 0.0f; o1[r] = 0.0f; }
  float m_run = -1e30f, l_run = 0.0f;
  const int qrow = qb + wave * 32 + l31;

  const __bf16* kbase = Kp + brow * 64;
  const __bf16* vb0 = Vt + (size_t)b * 262144 + (size_t)l31 * 4096 + half * 8;
  const __bf16* vb1 = vb0 + 32 * 4096;

  for (int it = it0; it < it1; ++it) {
    const int k0 = it * 64;
    // S^T = K @ Q^T, K-frags straight from global
    const __bf16* kp0 = kbase + (size_t)k0 * 64 + half * 8;
    floatx16 s0, s1;
#pragma unroll
    for (int r = 0; r < 16; r++) { s0[r] = 0.0f; s1[r] = 0.0f; }
#pragma unroll
    for (int ks = 0; ks < 4; ks++) {
      bf16x8 ka = *(const bf16x8*)(kp0 + l31 * 64 + ks * 16);
      bf16x8 kb = *(const bf16x8*)(kp0 + (32 + l31) * 64 + ks * 16);
      s0 = __builtin_amdgcn_mfma_f32_32x32x16_bf16(ka, qf[ks], s0, 0, 0, 0);
      s1 = __builtin_amdgcn_mfma_f32_32x32x16_bf16(kb, qf[ks], s1, 0, 0, 0);
    }
    // V^T fragments (A-operand: m=h, k=key) — issue early, consumed after softmax
    bf16x8 vfa[4], vfb[4];
#pragma unroll
    for (int kst = 0; kst < 4; kst++) {
      vfa[kst] = *(const bf16x8*)(vb0 + k0 + kst * 16);
      vfb[kst] = *(const bf16x8*)(vb1 + k0 + kst * 16);
    }
    if (k0 + 64 > qb) {  // diagonal: causal mask (key > q -> -inf)
#pragma unroll
      for (int r = 0; r < 16; r++) {
        int rs = (r & 3) + 8 * (r >> 2) + 4 * half;
        if (k0 + rs > qrow) s0[r] = -1e30f;
        if (k0 + 32 + rs > qrow) s1[r] = -1e30f;
      }
    }
    // online softmax: one q-row per lane (col=lane&31)
    float pm = -1e30f;
#pragma unroll
    for (int r = 0; r < 16; r++) { pm = fmaxf(pm, s0[r]); pm = fmaxf(pm, s1[r]); }
    pm = fmaxf(pm, __shfl_xor(pm, 32));
    float m_new = fmaxf(m_run, pm);
    float alpha = __builtin_amdgcn_exp2f(m_run - m_new);
    float psum = 0.0f;
#pragma unroll
    for (int r = 0; r < 16; r++) {
      s0[r] = __builtin_amdgcn_exp2f(s0[r] - m_new);
      s1[r] = __builtin_amdgcn_exp2f(s1[r] - m_new);
      psum += s0[r] + s1[r];
    }
    psum += __shfl_xor(psum, 32);
    l_run = l_run * alpha + psum;
    m_run = m_new;
#pragma unroll
    for (int r = 0; r < 16; r++) { o0[r] *= alpha; o1[r] *= alpha; }
    // pack P to bf16 pairs: pk[m] = (s[2m], s[2m+1])
    unsigned int pk0[8], pk1[8];
#pragma unroll
    for (int m = 0; m < 8; m++) {
      pk0[m] = (unsigned int)bf16bits(s0[2 * m]) | ((unsigned int)bf16bits(s0[2 * m + 1]) << 16);
      pk1[m] = (unsigned int)bf16bits(s1[2 * m]) | ((unsigned int)bf16bits(s1[2 * m + 1]) << 16);
    }
    // O^T += V^T @ P^T; B-frag built in-register (C-layout -> B-layout via shfl_xor 32)
#pragma unroll
    for (int kst = 0; kst < 4; ++kst) {
      const unsigned int* pkX = (kst < 2) ? pk0 : pk1;
      int bb2 = 4 * (kst & 1);
      unsigned int own0 = pkX[bb2 + 2 * half];
      unsigned int own1 = pkX[bb2 + 2 * half + 1];
      unsigned int u0 = pkX[bb2 + 2 * (1 - half)];
      unsigned int u1 = pkX[bb2 + 2 * (1 - half) + 1];
      unsigned int p0 = (unsigned int)__shfl_xor((int)u0, 32);
      unsigned int p1 = (unsigned int)__shfl_xor((int)u1, 32);
      uint4 fu = half ? make_uint4(p0, p1, own0, own1) : make_uint4(own0, own1, p0, p1);
      bf16x8 pf = __builtin_bit_cast(bf16x8, fu);
      o0 = __builtin_amdgcn_mfma_f32_32x32x16_bf16(vfa[kst], pf, o0, 0, 0, 0);
      o1 = __builtin_amdgcn_mfma_f32_32x32x16_bf16(vfb[kst], pf, o1, 0, 0, 0);
    }
  }
  // epilogue: transpose O^T -> Oe[q][h] in LDS, then coalesced partial store
#pragma unroll
  for (int r = 0; r < 16; r++) {
    int rs = (r & 3) + 8 * (r >> 2) + 4 * half;
    Oe[(wave * 32 + l31) * 68 + rs] = o0[r];
    Oe[(wave * 32 + l31) * 68 + 32 + rs] = o1[r];
  }
  if (lane < 32) {
    mlpart[(size_t)bid * 256 + wave * 32 + l31] = m_run;
    mlpart[(size_t)bid * 256 + 128 + wave * 32 + l31] = l_run;
  }
  __syncthreads();
  {
    float* dst = Opart + (size_t)bid * 8192;
    int r = tid >> 1, hh = (tid & 1) * 32;
#pragma unroll
    for (int i = 0; i < 8; i++)
      *(float4*)&dst[r * 64 + hh + 4 * i] = *(float4*)&Oe[r * 68 + hh + 4 * i];
  }
}

// ---------------- kernel 3: merge split partials, normalize ----------------
__global__ __launch_bounds__(256, 4) void attn2(const float* __restrict__ Opart,
                                                const float* __restrict__ mlpart,
                                                float* __restrict__ out) {
  const int bid = blockIdx.x;  // 0..511
  const int b = bid >> 7, rg = bid & 127;
  const int qt = rg >> 2;
  int cum = 0;
  for (int i = 0; i < qt; i++) cum += (i + 2) >> 1;
  const int S = (qt + 2) >> 1;
  const int t = threadIdx.x;
  const int r = t >> 3;
  const int prow = (rg & 3) * 32 + r;
  const int h0 = (t & 7) * 8;

  float M = -1e30f;
  for (int s = 0; s < S; s++)
    M = fmaxf(M, mlpart[(size_t)(b * NSPB + cum + s) * 256 + prow]);
  float a[8];
#pragma unroll
  for (int i = 0; i < 8; i++) a[i] = 0.0f;
  float L = 0.0f;
  for (int s = 0; s < S; s++) {
    size_t pb = (size_t)(b * NSPB + cum + s);
    float w = __builtin_amdgcn_exp2f(mlpart[pb * 256 + prow] - M);
    L += w * mlpart[pb * 256 + 128 + prow];
    const float* op = Opart + pb * 8192 + prow * 64 + h0;
    float4 v0 = *(const float4*)op;
    float4 v1 = *(const float4*)(op + 4);
    a[0] += w * v0.x; a[1] += w * v0.y; a[2] += w * v0.z; a[3] += w * v0.w;
    a[4] += w * v1.x; a[5] += w * v1.y; a[6] += w * v1.z; a[7] += w * v1.w;
  }
  float inv = 1.0f / L;
  float* po = out + ((size_t)b * 4096 + rg * 32 + r) * 64 + h0;
  float4 r0, r1;
  r0.x = a[0] * inv; r0.y = a[1] * inv; r0.z = a[2] * inv; r0.w = a[3] * inv;
  r1.x = a[4] * inv; r1.y = a[5] * inv; r1.z = a[6] * inv; r1.w = a[7] * inv;
  *(float4*)po = r0;
  *(float4*)(po + 4) = r1;
}

extern "C" void kernel_launch(void* const* d_in, const int* in_sizes, int n_in,
                              void* d_out, int out_size, void* d_ws, size_t ws_size,
                              hipStream_t stream) {
  (void)in_sizes; (void)n_in; (void)out_size; (void)ws_size;
  const float* x = (const float*)d_in[0];
  const float* Wq = (const float*)d_in[1];
  const float* Wk = (const float*)d_in[2];
  const float* Wv = (const float*)d_in[3];
  char* ws = (char*)d_ws;
  __bf16* Wtg = (__bf16*)(ws + WT_OFF);
  __bf16* Qp = (__bf16*)(ws + Q_OFF);
  __bf16* Kp = (__bf16*)(ws + K_OFF);
  __bf16* Vp = (__bf16*)(ws + V_OFF);
  __bf16* Vtp = (__bf16*)(ws + VT_OFF);
  float* Opart = (float*)(ws + OP_OFF);
  float* mlp = (float*)(ws + ML_OFF);
  float* out = (float*)d_out;

  hipLaunchKernelGGL(wprep, dim3(768), dim3(256), 0, stream, Wq, Wk, Wv, Wtg);
  hipLaunchKernelGGL(proj, dim3(1024), dim3(256), 0, stream, x, Wtg, Qp, Kp, Vp);
  hipLaunchKernelGGL(vtr, dim3(256), dim3(256), 0, stream, Vp, Vtp);
  hipLaunchKernelGGL(attn1, dim3(4 * NSPB), dim3(256), 0, stream, Qp, Kp, Vtp, Opart, mlp);
  hipLaunchKernelGGL(attn2, dim3(512), dim3(256), 0, stream, Opart, mlp, out);
}